// Round 12
// baseline (158.425 us; speedup 1.0000x reference)
//
#include <hip/hip_runtime.h>
#include <math.h>

#define KK 64
#define CAP 64
#define NF 4160      // 64 targets x (1 self + up to 64 in-edge slots)

// ---------------- Pass A (read-only): find edges incident to `node`; fused zeroing ----------------
__global__ __launch_bounds__(256) void k_find(const int* __restrict__ ei, int E,
                                              const int* __restrict__ nodep,
                                              int4* __restrict__ zbase, int zcount4,
                                              int* __restrict__ tcount,
                                              int* __restrict__ tpairs,
                                              float* __restrict__ h1s) {
    int idx = blockIdx.x * 256 + threadIdx.x;
    if (idx < zcount4) zbase[idx] = make_int4(0, 0, 0, 0);   // cnt/fmapRow/tflag/fcnt/tcnt2
    if (idx < 64) h1s[(size_t)NF * 64 + idx] = 0.f;          // zero row for branchless pads
    int node = nodep[0];
    int n4 = E >> 2;
    if (idx < n4) {
        int4 ss = ((const int4*)ei)[idx];
        int4 dd = ((const int4*)(ei + E))[idx];
        int s[4] = {ss.x, ss.y, ss.z, ss.w};
        int d[4] = {dd.x, dd.y, dd.z, dd.w};
#pragma unroll
        for (int k = 0; k < 4; k++) {
            if (s[k] == node || d[k] == node) {
                int q = atomicAdd(tcount, 1);
                if (q < KK) { int e = idx * 4 + k; tpairs[2 * q] = e; tpairs[2 * q + 1] = (s[k] == node) ? d[k] : s[k]; }
            }
        }
    }
    if (idx == 0) {
        for (int e = n4 * 4; e < E; e++) {
            int s = ei[e], d = ei[E + e];
            if (s == node || d == node) {
                int q = atomicAdd(tcount, 1);
                if (q < KK) { tpairs[2 * q] = e; tpairs[2 * q + 1] = (s == node) ? d : s; }
            }
        }
    }
}

// ---------------- Target sort (1 block): tsorted/towner + global tflag table ----------------
__global__ void k_tsort(const int* __restrict__ tpairs, int* __restrict__ tsorted,
                        int* __restrict__ towner, int* __restrict__ tflag) {
    __shared__ int eidx[KK], tgt[KK], srt[KK];
    int t = threadIdx.x;  // 64 threads
    eidx[t] = tpairs[2 * t];
    tgt[t] = tpairs[2 * t + 1];
    __syncthreads();
    int rank = 0;
    for (int j = 0; j < KK; j++) rank += (eidx[j] < eidx[t]) ? 1 : 0;
    srt[rank] = tgt[t];
    __syncthreads();
    int mynode = srt[t];
    int owner = t;
    for (int j = 0; j < t; j++) if (srt[j] == mynode) { owner = j; break; }
    tsorted[t] = mynode;
    towner[t] = owner;
    if (owner == t) tflag[mynode] = t + 1;
}

// ---------------- Pass B: collect target in-edges + HALF degree atomics ----------------
// No LDS: one independent global tflag load per edge (L2-resident 200KB table).
__global__ __launch_bounds__(256) void k_collect_t(const int* __restrict__ ei, int E,
                                                   const int* __restrict__ tflag,
                                                   int* __restrict__ cnt,
                                                   int* __restrict__ tcnt2,
                                                   int* __restrict__ tslots) {
    int idx = blockIdx.x * 256 + threadIdx.x;
    int n4 = E >> 2;
    if (idx < n4) {
        int4 ss = ((const int4*)ei)[idx];
        int4 dd = ((const int4*)(ei + E))[idx];
        int s[4] = {ss.x, ss.y, ss.z, ss.w};
        int d[4] = {dd.x, dd.y, dd.z, dd.w};
        atomicAdd(&cnt[d[0]], 1);   // half the degree atomics (k=0,1)
        atomicAdd(&cnt[d[1]], 1);
        int f0 = tflag[d[0]], f1 = tflag[d[1]], f2 = tflag[d[2]], f3 = tflag[d[3]];
        if (f0) { int p = atomicAdd(&tcnt2[f0 - 1], 1); if (p < CAP) tslots[(f0 - 1) * CAP + p] = s[0]; }
        if (f1) { int p = atomicAdd(&tcnt2[f1 - 1], 1); if (p < CAP) tslots[(f1 - 1) * CAP + p] = s[1]; }
        if (f2) { int p = atomicAdd(&tcnt2[f2 - 1], 1); if (p < CAP) tslots[(f2 - 1) * CAP + p] = s[2]; }
        if (f3) { int p = atomicAdd(&tcnt2[f3 - 1], 1); if (p < CAP) tslots[(f3 - 1) * CAP + p] = s[3]; }
    }
    if (idx == 0) {
        for (int e = n4 * 4; e < E; e++) {
            int d = ei[E + e];
            atomicAdd(&cnt[d], 1);
            int f = tflag[d];
            if (f) { int p = atomicAdd(&tcnt2[f - 1], 1); if (p < CAP) tslots[(f - 1) * CAP + p] = ei[e]; }
        }
    }
}

__device__ __forceinline__ int fnode_of(int i, const int* tsorted, const int* towner,
                                        const int* tcnt2, const int* tslots) {
    int tp = i / 65, j = i % 65;
    if (j == 0) return tsorted[tp];
    int own = towner[tp];
    int c = tcnt2[own]; if (c > CAP) c = CAP;
    return (j - 1 < c) ? tslots[own * CAP + (j - 1)] : -1;
}

// ---------------- Frontier build (once, 1 block): dedup via global CAS ----------------
__global__ __launch_bounds__(1024) void k_fbuild(const int* __restrict__ tsorted,
                                                 const int* __restrict__ towner,
                                                 const int* __restrict__ tcnt2,
                                                 const int* __restrict__ tslots,
                                                 int* __restrict__ fnode,
                                                 int* __restrict__ fmapRow,
                                                 int* __restrict__ fidx,
                                                 unsigned char* __restrict__ fown) {
    int tid = threadIdx.x;
    for (int i = tid; i < NF; i += 1024)
        fnode[i] = fnode_of(i, tsorted, towner, tcnt2, tslots);
    __syncthreads();
    for (int i = tid; i < NF; i += 1024) {
        int u = fnode[i];
        if (u >= 0) atomicCAS(&fmapRow[u], 0, i + 1);
    }
    __syncthreads();
    for (int i = tid; i < NF; i += 1024) {
        int u = fnode[i];
        if (u >= 0) {
            int row = fmapRow[u];
            fidx[i] = row - 1;
            fown[i] = (unsigned char)(row == i + 1);
        } else {
            fidx[i] = NF;      // zero row
            fown[i] = 0;
        }
    }
}

// ---------------- Pass C: collect frontier in-edges + other HALF degree atomics ----------------
__global__ __launch_bounds__(256) void k_collect_f(const int* __restrict__ ei, int E,
                                                   const int* __restrict__ fmapRow,
                                                   int* __restrict__ cnt,
                                                   int* __restrict__ fcnt,
                                                   int* __restrict__ fslots) {
    int idx = blockIdx.x * 256 + threadIdx.x;
    int n4 = E >> 2;
    if (idx < n4) {
        int4 ss = ((const int4*)ei)[idx];
        int4 dd = ((const int4*)(ei + E))[idx];
        int s[4] = {ss.x, ss.y, ss.z, ss.w};
        int d[4] = {dd.x, dd.y, dd.z, dd.w};
        atomicAdd(&cnt[d[2]], 1);   // other half of degree atomics (k=2,3)
        atomicAdd(&cnt[d[3]], 1);
        int r0 = fmapRow[d[0]], r1 = fmapRow[d[1]], r2 = fmapRow[d[2]], r3 = fmapRow[d[3]];
        if (r0) { int p = atomicAdd(&fcnt[r0 - 1], 1); if (p < CAP) fslots[(size_t)(r0 - 1) * CAP + p] = s[0]; }
        if (r1) { int p = atomicAdd(&fcnt[r1 - 1], 1); if (p < CAP) fslots[(size_t)(r1 - 1) * CAP + p] = s[1]; }
        if (r2) { int p = atomicAdd(&fcnt[r2 - 1], 1); if (p < CAP) fslots[(size_t)(r2 - 1) * CAP + p] = s[2]; }
        if (r3) { int p = atomicAdd(&fcnt[r3 - 1], 1); if (p < CAP) fslots[(size_t)(r3 - 1) * CAP + p] = s[3]; }
    }
    if (idx == 0) {
        for (int e = n4 * 4; e < E; e++) {
            int d = ei[E + e];
            atomicAdd(&cnt[d], 1);
            int r = fmapRow[d];
            if (r) { int p = atomicAdd(&fcnt[r - 1], 1); if (p < CAP) fslots[(size_t)(r - 1) * CAP + p] = ei[e]; }
        }
    }
}

// ---------------- Layer 1 (owner rows only): gather+norm x, W1 shfl-GEMM, relu, pre-scale ----------------
__global__ __launch_bounds__(256) void k_layer1(const float* __restrict__ x,
                                                const int* __restrict__ fnode,
                                                const unsigned char* __restrict__ fown,
                                                const int* __restrict__ cnt,
                                                const int* __restrict__ fcnt,
                                                const int* __restrict__ fslots,
                                                const float* __restrict__ W1,
                                                const float* __restrict__ b1,
                                                float* __restrict__ h1s) {
    __shared__ __align__(16) float W1s[64 * 64];
    int tid = threadIdx.x;
    for (int i = tid; i < 1024; i += 256) ((float4*)W1s)[i] = ((const float4*)W1)[i];
    __syncthreads();
    int i = blockIdx.x * 4 + (tid >> 6);
    int lane = tid & 63;
    if (i >= NF) return;
    if (!fown[i]) return;
    int u = fnode[i];
    float du = rsqrtf((float)(cnt[u] + 1));
    float acc = du * x[(size_t)u * 64 + lane];
    int c = fcnt[i]; if (c > CAP) c = CAP;
    const int* sl = fslots + (size_t)i * CAP;
    int k = 0;
    for (; k + 4 <= c; k += 4) {
        int u0 = sl[k], u1 = sl[k + 1], u2 = sl[k + 2], u3 = sl[k + 3];
        float f0 = rsqrtf((float)(cnt[u0] + 1));
        float f1 = rsqrtf((float)(cnt[u1] + 1));
        float f2 = rsqrtf((float)(cnt[u2] + 1));
        float f3 = rsqrtf((float)(cnt[u3] + 1));
        acc += f0 * x[(size_t)u0 * 64 + lane] + f1 * x[(size_t)u1 * 64 + lane]
             + f2 * x[(size_t)u2 * 64 + lane] + f3 * x[(size_t)u3 * 64 + lane];
    }
    for (; k < c; k++) {
        int uu = sl[k];
        acc += rsqrtf((float)(cnt[uu] + 1)) * x[(size_t)uu * 64 + lane];
    }
    float z = du * acc;
    float h = 0.f;
#pragma unroll
    for (int f = 0; f < 64; f++) h += __shfl(z, f) * W1s[f * 64 + lane];
    h = fmaxf(h + b1[lane], 0.f);
    h1s[(size_t)i * 64 + lane] = du * h;
}

// ---------------- Layer 2 + raw score: one block (one wave) per target ----------------
__global__ __launch_bounds__(64) void k_score2(const float* __restrict__ h1s,
                                               const int* __restrict__ fidx,
                                               const int* __restrict__ tsorted,
                                               const int* __restrict__ cnt,
                                               const float* __restrict__ W2,
                                               const float* __restrict__ b2,
                                               const float* __restrict__ Wr,
                                               float* __restrict__ sc) {
    int tp = blockIdx.x;
    int lane = threadIdx.x;
    int t = tsorted[tp];
    float dt = rsqrtf((float)(cnt[t] + 1));
    const int* fx = fidx + tp * 65;
    float z = 0.f;
#pragma unroll
    for (int j = 0; j < 65; j++) {
        int idx = fx[j];                      // wave-uniform -> scalar load
        z += h1s[(size_t)idx * 64 + lane];    // unconditional, independent
    }
    z *= dt;
    float acc = 0.f;
#pragma unroll
    for (int f = 0; f < 64; f++) acc += __shfl(z, f) * W2[f * 64 + lane];
    float h2 = fmaxf(acc + b2[lane], 0.f);
    float p = h2 * Wr[lane];
#pragma unroll
    for (int off = 32; off >= 1; off >>= 1) p += __shfl_xor(p, off);
    if (lane == 0) sc[tp] = p;   // br omitted: constant shift cancels in softmax
}

__global__ void k_softmax(const float* __restrict__ sc, const int* __restrict__ tsorted,
                          float* __restrict__ out) {
    int t = threadIdx.x;  // 64 threads
    float s = sc[t];
    float m = s;
#pragma unroll
    for (int off = 32; off >= 1; off >>= 1) m = fmaxf(m, __shfl_xor(m, off));
    float e = __expf(s - m);
    float ss = e;
#pragma unroll
    for (int off = 32; off >= 1; off >>= 1) ss += __shfl_xor(ss, off);
    out[t] = e / ss;
    out[KK + t] = (float)tsorted[t];
}

extern "C" void kernel_launch(void* const* d_in, const int* in_sizes, int n_in,
                              void* d_out, int out_size, void* d_ws, size_t ws_size,
                              hipStream_t stream) {
    const float* x  = (const float*)d_in[0];
    const int*   ei = (const int*)d_in[1];
    const int*   nodep = (const int*)d_in[2];
    const float* W1 = (const float*)d_in[3];
    const float* b1 = (const float*)d_in[4];
    const float* W2 = (const float*)d_in[5];
    const float* b2 = (const float*)d_in[6];
    const float* Wr = (const float*)d_in[7];
    const float* br = (const float*)d_in[8];
    float* out = (float*)d_out;
    (void)br;

    int N = in_sizes[0] / 64;   // 50000
    int E = in_sizes[1] / 2;    // 800064

    char* w = (char*)d_ws;
    // ---- region zeroed inside k_find (contiguous, int4-aligned) ----
    int* cnt     = (int*)w; w += (size_t)N * 4;    // in-degrees
    int* fmapRow = (int*)w; w += (size_t)N * 4;    // node -> owner entry+1 (CAS claim)
    int* tflag   = (int*)w; w += (size_t)N * 4;    // node -> target slot+1
    int* fcnt    = (int*)w; w += (size_t)NF * 4;
    int* tcnt2   = (int*)w; w += KK * 4;
    int zcount4 = (3 * N + NF + KK) / 4;           // 154224 ints -> 38556 int4
    // ---- zeroed by 16B memset (used by k_find itself) ----
    int* tcount = (int*)w; w += 16;
    // ---- non-zeroed ----
    int* tpairs  = (int*)w; w += 2 * KK * 4;
    int* tsorted = (int*)w; w += KK * 4;
    int* towner  = (int*)w; w += KK * 4;
    int* tslots  = (int*)w; w += (size_t)KK * CAP * 4;
    int* fnode   = (int*)w; w += (size_t)NF * 4;
    int* fidx    = (int*)w; w += (size_t)NF * 4;
    unsigned char* fown = (unsigned char*)w; w += (size_t)NF;
    w = (char*)(((size_t)w + 15) & ~(size_t)15);
    int* fslots  = (int*)w; w += (size_t)NF * CAP * 4;        // ~1.06 MB
    float* h1s   = (float*)w; w += (size_t)(NF + 1) * 64 * 4; // +1 zero row
    float* sc    = (float*)w; w += KK * 4;

    hipMemsetAsync(tcount, 0, 16, stream);

    int n4 = E >> 2;
    int ebl = (n4 + 255) / 256;
    k_find<<<ebl, 256, 0, stream>>>(ei, E, nodep, (int4*)cnt, zcount4, tcount, tpairs, h1s);
    k_tsort<<<1, 64, 0, stream>>>(tpairs, tsorted, towner, tflag);
    k_collect_t<<<ebl, 256, 0, stream>>>(ei, E, tflag, cnt, tcnt2, tslots);
    k_fbuild<<<1, 1024, 0, stream>>>(tsorted, towner, tcnt2, tslots, fnode, fmapRow, fidx, fown);
    k_collect_f<<<ebl, 256, 0, stream>>>(ei, E, fmapRow, cnt, fcnt, fslots);
    k_layer1<<<(NF + 3) / 4, 256, 0, stream>>>(x, fnode, fown, cnt, fcnt, fslots, W1, b1, h1s);
    k_score2<<<KK, 64, 0, stream>>>(h1s, fidx, tsorted, cnt, W2, b2, Wr, sc);
    k_softmax<<<1, 64, 0, stream>>>(sc, tsorted, out);
}

// Round 13
// 153.184 us; speedup vs baseline: 1.0342x; 1.0342x over previous
//
#include <hip/hip_runtime.h>
#include <math.h>

#define KK 64
#define CAP 64
#define NF 4160      // 64 targets x (1 self + up to 64 in-edge slots)
#define BMW 1568     // bitmask words for 50k nodes (50176 bits)

// ---------------- Pass A (read-only): find edges incident to `node`; fused zeroing ----------------
__global__ __launch_bounds__(256) void k_find(const int* __restrict__ ei, int E,
                                              const int* __restrict__ nodep,
                                              int4* __restrict__ zbase, int zcount4,
                                              int* __restrict__ tcount,
                                              int* __restrict__ tpairs,
                                              float* __restrict__ h1s) {
    int idx = blockIdx.x * 256 + threadIdx.x;
    if (idx < zcount4) zbase[idx] = make_int4(0, 0, 0, 0);   // cnt/fmapRow/fcnt/tcnt2
    if (idx < 64) h1s[(size_t)NF * 64 + idx] = 0.f;          // zero row for branchless pads
    int node = nodep[0];
    int n4 = E >> 2;
    if (idx < n4) {
        int4 ss = ((const int4*)ei)[idx];
        int4 dd = ((const int4*)(ei + E))[idx];
        int s[4] = {ss.x, ss.y, ss.z, ss.w};
        int d[4] = {dd.x, dd.y, dd.z, dd.w};
#pragma unroll
        for (int k = 0; k < 4; k++) {
            if (s[k] == node || d[k] == node) {
                int q = atomicAdd(tcount, 1);
                if (q < KK) { int e = idx * 4 + k; tpairs[2 * q] = e; tpairs[2 * q + 1] = (s[k] == node) ? d[k] : s[k]; }
            }
        }
    }
    if (idx == 0) {
        for (int e = n4 * 4; e < E; e++) {
            int s = ei[e], d = ei[E + e];
            if (s == node || d == node) {
                int q = atomicAdd(tcount, 1);
                if (q < KK) { tpairs[2 * q] = e; tpairs[2 * q + 1] = (s == node) ? d : s; }
            }
        }
    }
}

// ---------------- Pass B: collect target in-edges + HALF the degree atomics ----------------
// Per-block: 6.3KB LDS bitmask + 64-entry resolve list rebuilt from tpairs (cheap init).
__global__ __launch_bounds__(256) void k_collect_t(const int* __restrict__ ei, int E,
                                                   const int* __restrict__ tpairs,
                                                   int* __restrict__ cnt,
                                                   int* __restrict__ tcnt2,
                                                   int* __restrict__ tslots,
                                                   int* __restrict__ tsorted_g,
                                                   int* __restrict__ towner_g) {
    __shared__ unsigned int bmask[BMW];
    __shared__ int tnode[KK];
    __shared__ int eidx[KK], tgt[KK], srt[KK];
    int tid = threadIdx.x;
    for (int i = tid; i < BMW; i += 256) bmask[i] = 0u;
    if (tid < KK) { eidx[tid] = tpairs[2 * tid]; tgt[tid] = tpairs[2 * tid + 1]; }
    __syncthreads();
    if (tid < KK) {
        int rank = 0;
        for (int j = 0; j < KK; j++) rank += (eidx[j] < eidx[tid]) ? 1 : 0;
        srt[rank] = tgt[tid];
    }
    __syncthreads();
    if (tid < KK) {
        int mynode = srt[tid];
        int owner = tid;
        for (int j = 0; j < tid; j++) if (srt[j] == mynode) { owner = j; break; }
        tnode[tid] = (owner == tid) ? mynode : -1;
        if (owner == tid) atomicOr(&bmask[mynode >> 5], 1u << (mynode & 31));
        if (blockIdx.x == 0) { tsorted_g[tid] = mynode; towner_g[tid] = owner; }
    }
    __syncthreads();
    int n4 = E >> 2;
    for (int idx = blockIdx.x * 256 + tid; idx < n4; idx += gridDim.x * 256) {
        int4 ss = ((const int4*)ei)[idx];
        int4 dd = ((const int4*)(ei + E))[idx];
        int s[4] = {ss.x, ss.y, ss.z, ss.w};
        int d[4] = {dd.x, dd.y, dd.z, dd.w};
        atomicAdd(&cnt[d[0]], 1);   // half the degree atomics (k=0,1)
        atomicAdd(&cnt[d[1]], 1);
#pragma unroll
        for (int k = 0; k < 4; k++) {
            if ((bmask[d[k] >> 5] >> (d[k] & 31)) & 1u) {
                int f = 0;
                for (int j = 0; j < KK; j++) if (tnode[j] == d[k]) { f = j + 1; break; }
                if (f) { int p = atomicAdd(&tcnt2[f - 1], 1); if (p < CAP) tslots[(f - 1) * CAP + p] = s[k]; }
            }
        }
    }
    if (blockIdx.x == 0 && tid == 0) {
        for (int e = n4 * 4; e < E; e++) {
            int d = ei[E + e];
            atomicAdd(&cnt[d], 1);
            if ((bmask[d >> 5] >> (d & 31)) & 1u) {
                int f = 0;
                for (int j = 0; j < KK; j++) if (tnode[j] == d) { f = j + 1; break; }
                if (f) { int p = atomicAdd(&tcnt2[f - 1], 1); if (p < CAP) tslots[(f - 1) * CAP + p] = ei[e]; }
            }
        }
    }
}

__device__ __forceinline__ int fnode_of(int i, const int* tsorted, const int* towner,
                                        const int* tcnt2, const int* tslots) {
    int tp = i / 65, j = i % 65;
    if (j == 0) return tsorted[tp];
    int own = towner[tp];
    int c = tcnt2[own]; if (c > CAP) c = CAP;
    return (j - 1 < c) ? tslots[own * CAP + (j - 1)] : -1;
}

// ---------------- Frontier build (once, 1 block): dedup via global CAS ----------------
__global__ __launch_bounds__(1024) void k_fbuild(const int* __restrict__ tsorted,
                                                 const int* __restrict__ towner,
                                                 const int* __restrict__ tcnt2,
                                                 const int* __restrict__ tslots,
                                                 int* __restrict__ fnode,
                                                 int* __restrict__ fmapRow,
                                                 int* __restrict__ fidx,
                                                 unsigned char* __restrict__ fown) {
    int tid = threadIdx.x;
    for (int i = tid; i < NF; i += 1024)
        fnode[i] = fnode_of(i, tsorted, towner, tcnt2, tslots);
    __syncthreads();
    for (int i = tid; i < NF; i += 1024) {
        int u = fnode[i];
        if (u >= 0) atomicCAS(&fmapRow[u], 0, i + 1);
    }
    __syncthreads();
    for (int i = tid; i < NF; i += 1024) {
        int u = fnode[i];
        if (u >= 0) {
            int row = fmapRow[u];
            fidx[i] = row - 1;
            fown[i] = (unsigned char)(row == i + 1);
        } else {
            fidx[i] = NF;      // zero row
            fown[i] = 0;
        }
    }
}

// ---------------- Pass C: collect frontier in-edges + other HALF degree atomics ----------------
// No LDS: one independent global fmapRow load per edge (L2-resident 200KB table).
__global__ __launch_bounds__(256) void k_collect_f(const int* __restrict__ ei, int E,
                                                   const int* __restrict__ fmapRow,
                                                   int* __restrict__ cnt,
                                                   int* __restrict__ fcnt,
                                                   int* __restrict__ fslots) {
    int idx = blockIdx.x * 256 + threadIdx.x;
    int n4 = E >> 2;
    if (idx < n4) {
        int4 ss = ((const int4*)ei)[idx];
        int4 dd = ((const int4*)(ei + E))[idx];
        int s[4] = {ss.x, ss.y, ss.z, ss.w};
        int d[4] = {dd.x, dd.y, dd.z, dd.w};
        atomicAdd(&cnt[d[2]], 1);   // other half of degree atomics (k=2,3)
        atomicAdd(&cnt[d[3]], 1);
        int r0 = fmapRow[d[0]], r1 = fmapRow[d[1]], r2 = fmapRow[d[2]], r3 = fmapRow[d[3]];
        if (r0) { int p = atomicAdd(&fcnt[r0 - 1], 1); if (p < CAP) fslots[(size_t)(r0 - 1) * CAP + p] = s[0]; }
        if (r1) { int p = atomicAdd(&fcnt[r1 - 1], 1); if (p < CAP) fslots[(size_t)(r1 - 1) * CAP + p] = s[1]; }
        if (r2) { int p = atomicAdd(&fcnt[r2 - 1], 1); if (p < CAP) fslots[(size_t)(r2 - 1) * CAP + p] = s[2]; }
        if (r3) { int p = atomicAdd(&fcnt[r3 - 1], 1); if (p < CAP) fslots[(size_t)(r3 - 1) * CAP + p] = s[3]; }
    }
    if (idx == 0) {
        for (int e = n4 * 4; e < E; e++) {
            int d = ei[E + e];
            atomicAdd(&cnt[d], 1);
            int r = fmapRow[d];
            if (r) { int p = atomicAdd(&fcnt[r - 1], 1); if (p < CAP) fslots[(size_t)(r - 1) * CAP + p] = ei[e]; }
        }
    }
}

// ---------------- Layer 1 (owner rows only): early block-exit, then W1 shfl-GEMM ----------------
__global__ __launch_bounds__(256) void k_layer1(const float* __restrict__ x,
                                                const int* __restrict__ fnode,
                                                const unsigned char* __restrict__ fown,
                                                const int* __restrict__ cnt,
                                                const int* __restrict__ fcnt,
                                                const int* __restrict__ fslots,
                                                const float* __restrict__ W1,
                                                const float* __restrict__ b1,
                                                float* __restrict__ h1s) {
    __shared__ __align__(16) float W1s[64 * 64];
    __shared__ int anyown;
    int tid = threadIdx.x;
    int i = blockIdx.x * 4 + (tid >> 6);
    int lane = tid & 63;
    int own = (i < NF) ? (int)fown[i] : 0;
    if (tid == 0) anyown = 0;
    __syncthreads();
    if (lane == 0 && own) anyown = 1;
    __syncthreads();
    if (!anyown) return;                      // ~70% of blocks: all 4 rows are pads/dups
    for (int j = tid; j < 1024; j += 256) ((float4*)W1s)[j] = ((const float4*)W1)[j];
    __syncthreads();
    if (!own) return;
    int u = fnode[i];
    float du = rsqrtf((float)(cnt[u] + 1));
    float acc = du * x[(size_t)u * 64 + lane];
    int c = fcnt[i]; if (c > CAP) c = CAP;
    const int* sl = fslots + (size_t)i * CAP;
    int k = 0;
    for (; k + 4 <= c; k += 4) {
        int u0 = sl[k], u1 = sl[k + 1], u2 = sl[k + 2], u3 = sl[k + 3];
        float f0 = rsqrtf((float)(cnt[u0] + 1));
        float f1 = rsqrtf((float)(cnt[u1] + 1));
        float f2 = rsqrtf((float)(cnt[u2] + 1));
        float f3 = rsqrtf((float)(cnt[u3] + 1));
        acc += f0 * x[(size_t)u0 * 64 + lane] + f1 * x[(size_t)u1 * 64 + lane]
             + f2 * x[(size_t)u2 * 64 + lane] + f3 * x[(size_t)u3 * 64 + lane];
    }
    for (; k < c; k++) {
        int uu = sl[k];
        acc += rsqrtf((float)(cnt[uu] + 1)) * x[(size_t)uu * 64 + lane];
    }
    float z = du * acc;
    float h = 0.f;
#pragma unroll
    for (int f = 0; f < 64; f++) h += __shfl(z, f) * W1s[f * 64 + lane];
    h = fmaxf(h + b1[lane], 0.f);
    h1s[(size_t)i * 64 + lane] = du * h;
}

// ---------------- Layer 2 + raw score: one block (one wave) per target; bounded row loop ----------------
__global__ __launch_bounds__(64) void k_score2(const float* __restrict__ h1s,
                                               const int* __restrict__ fidx,
                                               const int* __restrict__ tsorted,
                                               const int* __restrict__ towner,
                                               const int* __restrict__ tcnt2,
                                               const int* __restrict__ cnt,
                                               const float* __restrict__ W2,
                                               const float* __restrict__ b2,
                                               const float* __restrict__ Wr,
                                               float* __restrict__ sc) {
    int tp = blockIdx.x;
    int lane = threadIdx.x;
    int t = tsorted[tp];
    float dt = rsqrtf((float)(cnt[t] + 1));
    int c = tcnt2[towner[tp]]; if (c > CAP) c = CAP;
    int jmax = 1 + c;                         // valid prefix of the 65-row band
    const int* fx = fidx + tp * 65;
    float z = 0.f;
#pragma unroll 8
    for (int j = 0; j < jmax; j++) {
        int idx = fx[j];                      // wave-uniform -> scalar load
        z += h1s[(size_t)idx * 64 + lane];    // unconditional, independent
    }
    z *= dt;
    float acc = 0.f;
#pragma unroll
    for (int f = 0; f < 64; f++) acc += __shfl(z, f) * W2[f * 64 + lane];
    float h2 = fmaxf(acc + b2[lane], 0.f);
    float p = h2 * Wr[lane];
#pragma unroll
    for (int off = 32; off >= 1; off >>= 1) p += __shfl_xor(p, off);
    if (lane == 0) sc[tp] = p;   // br omitted: constant shift cancels in softmax
}

__global__ void k_softmax(const float* __restrict__ sc, const int* __restrict__ tsorted,
                          float* __restrict__ out) {
    int t = threadIdx.x;  // 64 threads
    float s = sc[t];
    float m = s;
#pragma unroll
    for (int off = 32; off >= 1; off >>= 1) m = fmaxf(m, __shfl_xor(m, off));
    float e = __expf(s - m);
    float ss = e;
#pragma unroll
    for (int off = 32; off >= 1; off >>= 1) ss += __shfl_xor(ss, off);
    out[t] = e / ss;
    out[KK + t] = (float)tsorted[t];
}

extern "C" void kernel_launch(void* const* d_in, const int* in_sizes, int n_in,
                              void* d_out, int out_size, void* d_ws, size_t ws_size,
                              hipStream_t stream) {
    const float* x  = (const float*)d_in[0];
    const int*   ei = (const int*)d_in[1];
    const int*   nodep = (const int*)d_in[2];
    const float* W1 = (const float*)d_in[3];
    const float* b1 = (const float*)d_in[4];
    const float* W2 = (const float*)d_in[5];
    const float* b2 = (const float*)d_in[6];
    const float* Wr = (const float*)d_in[7];
    const float* br = (const float*)d_in[8];
    float* out = (float*)d_out;
    (void)br;

    int N = in_sizes[0] / 64;   // 50000
    int E = in_sizes[1] / 2;    // 800064

    char* w = (char*)d_ws;
    // ---- region zeroed inside k_find (contiguous, int4-aligned) ----
    int* cnt     = (int*)w; w += (size_t)N * 4;    // in-degrees
    int* fmapRow = (int*)w; w += (size_t)N * 4;    // node -> owner entry+1 (CAS claim)
    int* fcnt    = (int*)w; w += (size_t)NF * 4;
    int* tcnt2   = (int*)w; w += KK * 4;
    int zcount4 = (2 * N + NF + KK) / 4;           // 104224 ints -> 26056 int4
    // ---- zeroed by 16B memset (used by k_find itself) ----
    int* tcount = (int*)w; w += 16;
    // ---- non-zeroed ----
    int* tpairs  = (int*)w; w += 2 * KK * 4;
    int* tsorted = (int*)w; w += KK * 4;
    int* towner  = (int*)w; w += KK * 4;
    int* tslots  = (int*)w; w += (size_t)KK * CAP * 4;
    int* fnode   = (int*)w; w += (size_t)NF * 4;
    int* fidx    = (int*)w; w += (size_t)NF * 4;
    unsigned char* fown = (unsigned char*)w; w += (size_t)NF;
    w = (char*)(((size_t)w + 15) & ~(size_t)15);
    int* fslots  = (int*)w; w += (size_t)NF * CAP * 4;        // ~1.06 MB
    float* h1s   = (float*)w; w += (size_t)(NF + 1) * 64 * 4; // +1 zero row
    float* sc    = (float*)w; w += KK * 4;

    hipMemsetAsync(tcount, 0, 16, stream);

    int n4 = E >> 2;
    int ebl = (n4 + 255) / 256;
    k_find<<<ebl, 256, 0, stream>>>(ei, E, nodep, (int4*)cnt, zcount4, tcount, tpairs, h1s);
    k_collect_t<<<512, 256, 0, stream>>>(ei, E, tpairs, cnt, tcnt2, tslots, tsorted, towner);
    k_fbuild<<<1, 1024, 0, stream>>>(tsorted, towner, tcnt2, tslots, fnode, fmapRow, fidx, fown);
    k_collect_f<<<ebl, 256, 0, stream>>>(ei, E, fmapRow, cnt, fcnt, fslots);
    k_layer1<<<(NF + 3) / 4, 256, 0, stream>>>(x, fnode, fown, cnt, fcnt, fslots, W1, b1, h1s);
    k_score2<<<KK, 64, 0, stream>>>(h1s, fidx, tsorted, towner, tcnt2, cnt, W2, b2, Wr, sc);
    k_softmax<<<1, 64, 0, stream>>>(sc, tsorted, out);
}

// Round 14
// 146.653 us; speedup vs baseline: 1.0803x; 1.0445x over previous
//
#include <hip/hip_runtime.h>
#include <math.h>

#define KK 64
#define CAP 64
#define NF 4160      // 64 targets x (1 self + up to 64 in-edge slots)
#define BMW 1568     // bitmask words for 50k nodes (50176 bits)

// ---------------- Pass A (read-only): find edges incident to `node`; fused zeroing ----------------
__global__ __launch_bounds__(256) void k_find(const int* __restrict__ ei, int E,
                                              const int* __restrict__ nodep,
                                              int4* __restrict__ zbase, int zcount4,
                                              int* __restrict__ tcount,
                                              int* __restrict__ tpairs) {
    int idx = blockIdx.x * 256 + threadIdx.x;
    if (idx < zcount4) zbase[idx] = make_int4(0, 0, 0, 0);   // cnt/fmapRow/fcnt/tcnt2
    int node = nodep[0];
    int n4 = E >> 2;
    if (idx < n4) {
        int4 ss = ((const int4*)ei)[idx];
        int4 dd = ((const int4*)(ei + E))[idx];
        int s[4] = {ss.x, ss.y, ss.z, ss.w};
        int d[4] = {dd.x, dd.y, dd.z, dd.w};
#pragma unroll
        for (int k = 0; k < 4; k++) {
            if (s[k] == node || d[k] == node) {
                int q = atomicAdd(tcount, 1);
                if (q < KK) { int e = idx * 4 + k; tpairs[2 * q] = e; tpairs[2 * q + 1] = (s[k] == node) ? d[k] : s[k]; }
            }
        }
    }
    if (idx == 0) {
        for (int e = n4 * 4; e < E; e++) {
            int s = ei[e], d = ei[E + e];
            if (s == node || d == node) {
                int q = atomicAdd(tcount, 1);
                if (q < KK) { tpairs[2 * q] = e; tpairs[2 * q + 1] = (s == node) ? d : s; }
            }
        }
    }
}

// ---------------- Pass B: target collect + HALF degree atomics + fmapRow claims ----------------
// Per-block: 6.3KB LDS bitmask + 64-entry resolve list rebuilt from tpairs (cheap init).
// Appends CAS-claim fmapRow[s] = band_row+1 (first-wins, output-invariant).
__global__ __launch_bounds__(256) void k_collect_t(const int* __restrict__ ei, int E,
                                                   const int* __restrict__ tpairs,
                                                   int* __restrict__ cnt,
                                                   int* __restrict__ tcnt2,
                                                   int* __restrict__ tslots,
                                                   int* __restrict__ fmapRow,
                                                   int* __restrict__ tsorted_g,
                                                   int* __restrict__ towner_g) {
    __shared__ unsigned int bmask[BMW];
    __shared__ int tnode[KK];
    __shared__ int eidx[KK], tgt[KK], srt[KK];
    int tid = threadIdx.x;
    for (int i = tid; i < BMW; i += 256) bmask[i] = 0u;
    if (tid < KK) { eidx[tid] = tpairs[2 * tid]; tgt[tid] = tpairs[2 * tid + 1]; }
    __syncthreads();
    if (tid < KK) {
        int rank = 0;
        for (int j = 0; j < KK; j++) rank += (eidx[j] < eidx[tid]) ? 1 : 0;
        srt[rank] = tgt[tid];
    }
    __syncthreads();
    if (tid < KK) {
        int mynode = srt[tid];
        int owner = tid;
        for (int j = 0; j < tid; j++) if (srt[j] == mynode) { owner = j; break; }
        tnode[tid] = (owner == tid) ? mynode : -1;
        if (owner == tid) atomicOr(&bmask[mynode >> 5], 1u << (mynode & 31));
        if (blockIdx.x == 0) {
            tsorted_g[tid] = mynode; towner_g[tid] = owner;
            if (owner == tid) atomicCAS(&fmapRow[mynode], 0, tid * 65 + 0 + 1);  // self row claim
        }
    }
    __syncthreads();
    int n4 = E >> 2;
    for (int idx = blockIdx.x * 256 + tid; idx < n4; idx += gridDim.x * 256) {
        int4 ss = ((const int4*)ei)[idx];
        int4 dd = ((const int4*)(ei + E))[idx];
        int s[4] = {ss.x, ss.y, ss.z, ss.w};
        int d[4] = {dd.x, dd.y, dd.z, dd.w};
        atomicAdd(&cnt[d[0]], 1);   // half the degree atomics (k=0,1)
        atomicAdd(&cnt[d[1]], 1);
#pragma unroll
        for (int k = 0; k < 4; k++) {
            if ((bmask[d[k] >> 5] >> (d[k] & 31)) & 1u) {
                int f = 0;
                for (int j = 0; j < KK; j++) if (tnode[j] == d[k]) { f = j + 1; break; }
                if (f) {
                    int p = atomicAdd(&tcnt2[f - 1], 1);
                    if (p < CAP) {
                        tslots[(f - 1) * CAP + p] = s[k];
                        atomicCAS(&fmapRow[s[k]], 0, (f - 1) * 65 + (p + 1) + 1);  // slot row claim
                    }
                }
            }
        }
    }
    if (blockIdx.x == 0 && tid == 0) {
        for (int e = n4 * 4; e < E; e++) {
            int d = ei[E + e];
            atomicAdd(&cnt[d], 1);
            if ((bmask[d >> 5] >> (d & 31)) & 1u) {
                int f = 0;
                for (int j = 0; j < KK; j++) if (tnode[j] == d) { f = j + 1; break; }
                if (f) {
                    int p = atomicAdd(&tcnt2[f - 1], 1);
                    if (p < CAP) {
                        tslots[(f - 1) * CAP + p] = ei[e];
                        atomicCAS(&fmapRow[ei[e]], 0, (f - 1) * 65 + (p + 1) + 1);
                    }
                }
            }
        }
    }
}

__device__ __forceinline__ int fnode_of(int i, const int* tsorted, const int* towner,
                                        const int* tcnt2, const int* tslots) {
    int tp = i / 65, j = i % 65;
    if (j == 0) return tsorted[tp];
    int own = towner[tp];
    int c = tcnt2[own]; if (c > CAP) c = CAP;
    return (j - 1 < c) ? tslots[own * CAP + (j - 1)] : -1;
}

// ---------------- Pass C: frontier collect + other HALF degree atomics ----------------
// One independent global fmapRow load per edge (L2-resident 200KB table).
__global__ __launch_bounds__(256) void k_collect_f(const int* __restrict__ ei, int E,
                                                   const int* __restrict__ fmapRow,
                                                   int* __restrict__ cnt,
                                                   int* __restrict__ fcnt,
                                                   int* __restrict__ fslots) {
    int idx = blockIdx.x * 256 + threadIdx.x;
    int n4 = E >> 2;
    if (idx < n4) {
        int4 ss = ((const int4*)ei)[idx];
        int4 dd = ((const int4*)(ei + E))[idx];
        int s[4] = {ss.x, ss.y, ss.z, ss.w};
        int d[4] = {dd.x, dd.y, dd.z, dd.w};
        atomicAdd(&cnt[d[2]], 1);   // other half of degree atomics (k=2,3)
        atomicAdd(&cnt[d[3]], 1);
        int r0 = fmapRow[d[0]], r1 = fmapRow[d[1]], r2 = fmapRow[d[2]], r3 = fmapRow[d[3]];
        if (r0) { int p = atomicAdd(&fcnt[r0 - 1], 1); if (p < CAP) fslots[(size_t)(r0 - 1) * CAP + p] = s[0]; }
        if (r1) { int p = atomicAdd(&fcnt[r1 - 1], 1); if (p < CAP) fslots[(size_t)(r1 - 1) * CAP + p] = s[1]; }
        if (r2) { int p = atomicAdd(&fcnt[r2 - 1], 1); if (p < CAP) fslots[(size_t)(r2 - 1) * CAP + p] = s[2]; }
        if (r3) { int p = atomicAdd(&fcnt[r3 - 1], 1); if (p < CAP) fslots[(size_t)(r3 - 1) * CAP + p] = s[3]; }
    }
    if (idx == 0) {
        for (int e = n4 * 4; e < E; e++) {
            int r = fmapRow[ei[E + e]];   // tail cnt handled in collect_t
            if (r) { int p = atomicAdd(&fcnt[r - 1], 1); if (p < CAP) fslots[(size_t)(r - 1) * CAP + p] = ei[e]; }
        }
    }
}

// ---------------- Layer 1 (owner rows only): inline fnode, gather+norm, W1 shfl-GEMM ----------------
__global__ __launch_bounds__(256) void k_layer1(const float* __restrict__ x,
                                                const int* __restrict__ tsorted,
                                                const int* __restrict__ towner,
                                                const int* __restrict__ tcnt2,
                                                const int* __restrict__ tslots,
                                                const int* __restrict__ fmapRow,
                                                const int* __restrict__ cnt,
                                                const int* __restrict__ fcnt,
                                                const int* __restrict__ fslots,
                                                const float* __restrict__ W1,
                                                const float* __restrict__ b1,
                                                float* __restrict__ h1s) {
    __shared__ __align__(16) float W1s[64 * 64];
    __shared__ int anyown;
    int tid = threadIdx.x;
    int i = blockIdx.x * 4 + (tid >> 6);
    int lane = tid & 63;
    int u = -1, own = 0;
    if (i < NF) {
        u = fnode_of(i, tsorted, towner, tcnt2, tslots);
        if (u >= 0) own = (fmapRow[u] == i + 1);
    }
    if (tid == 0) anyown = 0;
    __syncthreads();
    if (lane == 0 && own) anyown = 1;
    __syncthreads();
    if (!anyown) return;                      // ~70% of blocks: all 4 rows pads/dups
    for (int j = tid; j < 1024; j += 256) ((float4*)W1s)[j] = ((const float4*)W1)[j];
    __syncthreads();
    if (!own) return;
    float du = rsqrtf((float)(cnt[u] + 1));
    float acc = du * x[(size_t)u * 64 + lane];
    int c = fcnt[i]; if (c > CAP) c = CAP;
    const int* sl = fslots + (size_t)i * CAP;
    int k = 0;
    for (; k + 4 <= c; k += 4) {
        int u0 = sl[k], u1 = sl[k + 1], u2 = sl[k + 2], u3 = sl[k + 3];
        float f0 = rsqrtf((float)(cnt[u0] + 1));
        float f1 = rsqrtf((float)(cnt[u1] + 1));
        float f2 = rsqrtf((float)(cnt[u2] + 1));
        float f3 = rsqrtf((float)(cnt[u3] + 1));
        acc += f0 * x[(size_t)u0 * 64 + lane] + f1 * x[(size_t)u1 * 64 + lane]
             + f2 * x[(size_t)u2 * 64 + lane] + f3 * x[(size_t)u3 * 64 + lane];
    }
    for (; k < c; k++) {
        int uu = sl[k];
        acc += rsqrtf((float)(cnt[uu] + 1)) * x[(size_t)uu * 64 + lane];
    }
    float z = du * acc;
    float h = 0.f;
#pragma unroll
    for (int f = 0; f < 64; f++) h += __shfl(z, f) * W1s[f * 64 + lane];
    h = fmaxf(h + b1[lane], 0.f);
    h1s[(size_t)i * 64 + lane] = du * h;
}

// ---------------- Layer 2 + raw score: one block (one wave) per target; bounded row loop ----------------
__global__ __launch_bounds__(64) void k_score2(const float* __restrict__ h1s,
                                               const int* __restrict__ tsorted,
                                               const int* __restrict__ towner,
                                               const int* __restrict__ tcnt2,
                                               const int* __restrict__ tslots,
                                               const int* __restrict__ fmapRow,
                                               const int* __restrict__ cnt,
                                               const float* __restrict__ W2,
                                               const float* __restrict__ b2,
                                               const float* __restrict__ Wr,
                                               float* __restrict__ sc) {
    int tp = blockIdx.x;
    int lane = threadIdx.x;
    int t = tsorted[tp];
    float dt = rsqrtf((float)(cnt[t] + 1));
    int own = towner[tp];
    int c = tcnt2[own]; if (c > CAP) c = CAP;
    const int* sl = tslots + own * CAP;
    // j=0: self row via fmapRow[t]
    float z = h1s[(size_t)(fmapRow[t] - 1) * 64 + lane];
#pragma unroll 8
    for (int j = 0; j < c; j++) {
        int u = sl[j];                        // wave-uniform scalar loads, independent
        int row = fmapRow[u] - 1;             // depth-2 chain, pipelined across j
        z += h1s[(size_t)row * 64 + lane];
    }
    z *= dt;
    float acc = 0.f;
#pragma unroll
    for (int f = 0; f < 64; f++) acc += __shfl(z, f) * W2[f * 64 + lane];
    float h2 = fmaxf(acc + b2[lane], 0.f);
    float p = h2 * Wr[lane];
#pragma unroll
    for (int off = 32; off >= 1; off >>= 1) p += __shfl_xor(p, off);
    if (lane == 0) sc[tp] = p;   // br omitted: constant shift cancels in softmax
}

__global__ void k_softmax(const float* __restrict__ sc, const int* __restrict__ tsorted,
                          float* __restrict__ out) {
    int t = threadIdx.x;  // 64 threads
    float s = sc[t];
    float m = s;
#pragma unroll
    for (int off = 32; off >= 1; off >>= 1) m = fmaxf(m, __shfl_xor(m, off));
    float e = __expf(s - m);
    float ss = e;
#pragma unroll
    for (int off = 32; off >= 1; off >>= 1) ss += __shfl_xor(ss, off);
    out[t] = e / ss;
    out[KK + t] = (float)tsorted[t];
}

extern "C" void kernel_launch(void* const* d_in, const int* in_sizes, int n_in,
                              void* d_out, int out_size, void* d_ws, size_t ws_size,
                              hipStream_t stream) {
    const float* x  = (const float*)d_in[0];
    const int*   ei = (const int*)d_in[1];
    const int*   nodep = (const int*)d_in[2];
    const float* W1 = (const float*)d_in[3];
    const float* b1 = (const float*)d_in[4];
    const float* W2 = (const float*)d_in[5];
    const float* b2 = (const float*)d_in[6];
    const float* Wr = (const float*)d_in[7];
    const float* br = (const float*)d_in[8];
    float* out = (float*)d_out;
    (void)br;

    int N = in_sizes[0] / 64;   // 50000
    int E = in_sizes[1] / 2;    // 800064

    char* w = (char*)d_ws;
    // ---- region zeroed inside k_find (contiguous, int4-aligned) ----
    int* cnt     = (int*)w; w += (size_t)N * 4;    // in-degrees
    int* fmapRow = (int*)w; w += (size_t)N * 4;    // node -> band row+1 (CAS claim)
    int* fcnt    = (int*)w; w += (size_t)NF * 4;
    int* tcnt2   = (int*)w; w += KK * 4;
    int zcount4 = (2 * N + NF + KK) / 4;           // 104224 ints -> 26056 int4
    // ---- zeroed by 16B memset (used by k_find itself) ----
    int* tcount = (int*)w; w += 16;
    // ---- non-zeroed ----
    int* tpairs  = (int*)w; w += 2 * KK * 4;
    int* tsorted = (int*)w; w += KK * 4;
    int* towner  = (int*)w; w += KK * 4;
    int* tslots  = (int*)w; w += (size_t)KK * CAP * 4;
    int* fslots  = (int*)w; w += (size_t)NF * CAP * 4;    // ~1.06 MB
    float* h1s   = (float*)w; w += (size_t)NF * 64 * 4;   // ~1.06 MB
    float* sc    = (float*)w; w += KK * 4;

    hipMemsetAsync(tcount, 0, 16, stream);

    int n4 = E >> 2;
    int ebl = (n4 + 255) / 256;
    k_find<<<ebl, 256, 0, stream>>>(ei, E, nodep, (int4*)cnt, zcount4, tcount, tpairs);
    k_collect_t<<<512, 256, 0, stream>>>(ei, E, tpairs, cnt, tcnt2, tslots, fmapRow, tsorted, towner);
    k_collect_f<<<ebl, 256, 0, stream>>>(ei, E, fmapRow, cnt, fcnt, fslots);
    k_layer1<<<(NF + 3) / 4, 256, 0, stream>>>(x, tsorted, towner, tcnt2, tslots, fmapRow,
                                               cnt, fcnt, fslots, W1, b1, h1s);
    k_score2<<<KK, 64, 0, stream>>>(h1s, tsorted, towner, tcnt2, tslots, fmapRow,
                                    cnt, W2, b2, Wr, sc);
    k_softmax<<<1, 64, 0, stream>>>(sc, tsorted, out);
}